// Round 5
// baseline (135.598 us; speedup 1.0000x reference)
//
#include <hip/hip_runtime.h>

#define SIGMA 0.5f
#define BB 32
#define NVV 6890
#define NFF 13776
#define MAXC 8
#define NCC (NFF * MAXC)                 // 110208 pairs per batch

// fused kernel geometry: one block per (batch, slot); 16 slots per batch.
// LDS = verts only (55.2 KB) -> 2 blocks/CU, 8 waves/SIMD (2048 thr/CU cap).
#define SLOTS 16
#define PAIRS_PER_SLOT (NCC / SLOTS)     // 6888 exactly
#define QUADS (PAIRS_PER_SLOT / 2)       // 3444 int4-quads (2 pairs each)
#define THREADS 1024
#define NBLOCK (BB * SLOTS)              // 512 blocks

// workspace layout: packed face table (u64 recs), then partials
#define FTAB_BYTES ((size_t)NFF * 8)     // 110,208 B
#define WS_NEED (FTAB_BYTES + (size_t)NBLOCK * 4 + 64)

typedef int       v4i __attribute__((ext_vector_type(4)));
typedef _Float16  h4  __attribute__((ext_vector_type(4)));

__device__ __forceinline__ float3 loadv3(const float* __restrict__ p) {
    return make_float3(p[0], p[1], p[2]);
}

// raw-instruction transcendentals (v_sqrt_f32 / v_rcp_f32, ~1 ulp)
__device__ __forceinline__ float fsqrt(float x) { return __builtin_amdgcn_sqrtf(x); }
__device__ __forceinline__ float frcp(float x)  { return __builtin_amdgcn_rcpf(x); }

// one-sided conic penetration, BRANCHLESS (round-3 known-good f32 core)
__device__ __forceinline__ float coneSide(float cx, float cy, float cz,
                                          float nx, float ny, float nz,
                                          float3 q0, float3 q1, float3 q2) {
    float pen = 0.0f;
#pragma unroll
    for (int v = 0; v < 3; ++v) {
        float3 q = (v == 0) ? q0 : ((v == 1) ? q1 : q2);
        float dx = q.x - cx, dy = q.y - cy, dz = q.z - cz;
        float h  = dx * nx + dy * ny + dz * nz;
        float r2 = dx * dx + dy * dy + dz * dz;
        float r  = fsqrt(r2);
        float phi = fmaxf(SIGMA - r, 0.0f);
        float hm  = fminf(h, 0.0f);          // (h<0 ? phi*h*h : 0) == phi*hm*hm
        pen = fmaf(phi * hm, hm, pen);
    }
    return pen;
}

__device__ __forceinline__ float triPairPen(float3 A0, float3 A1, float3 A2,
                                            float3 B0, float3 B1, float3 B2) {
    const float third = 1.0f / 3.0f;
    float cax = (A0.x + A1.x + A2.x) * third;
    float cay = (A0.y + A1.y + A2.y) * third;
    float caz = (A0.z + A1.z + A2.z) * third;
    float cbx = (B0.x + B1.x + B2.x) * third;
    float cby = (B0.y + B1.y + B2.y) * third;
    float cbz = (B0.z + B1.z + B2.z) * third;
    float e1x = A1.x - A0.x, e1y = A1.y - A0.y, e1z = A1.z - A0.z;
    float e2x = A2.x - A0.x, e2y = A2.y - A0.y, e2z = A2.z - A0.z;
    float nax = e1y * e2z - e1z * e2y;
    float nay = e1z * e2x - e1x * e2z;
    float naz = e1x * e2y - e1y * e2x;
    float inva = frcp(fsqrt(nax * nax + nay * nay + naz * naz) + 1e-8f);
    nax *= inva; nay *= inva; naz *= inva;
    float f1x = B1.x - B0.x, f1y = B1.y - B0.y, f1z = B1.z - B0.z;
    float f2x = B2.x - B0.x, f2y = B2.y - B0.y, f2z = B2.z - B0.z;
    float nbx = f1y * f2z - f1z * f2y;
    float nby = f1z * f2x - f1x * f2z;
    float nbz = f1x * f2y - f1y * f2x;
    float invb = frcp(fsqrt(nbx * nbx + nby * nby + nbz * nbz) + 1e-8f);
    nbx *= invb; nby *= invb; nbz *= invb;

    return coneSide(cax, cay, caz, nax, nay, naz, B0, B1, B2)
         + coneSide(cbx, cby, cbz, nbx, nby, nbz, A0, A1, A2);
}

// load one packed-f16 vertex by PRE-SHIFTED byte offset (one ds_read_b64)
__device__ __forceinline__ float3 ldsVertB(const h4* __restrict__ sv, unsigned int boff) {
    h4 h = *(const h4*)((const char*)sv + boff);
    return make_float3((float)h.x, (float)h.y, (float)h.z);
}

// branchless pair eval: face offsets from GLOBAL packed table (L2-warm),
// vertices from LDS. Invalid (r<0) masked with one cndmask.
__device__ __forceinline__ float pairPen(const h4*   __restrict__ sv,
                                         const uint2* __restrict__ ftab,
                                         int r, int it) {
    const int rr = r  < 0 ? 0 : r;
    const int g  = it < 0 ? 0 : it;       // reference clamps with max(idx,0)
    uint2 fa = ftab[rr];                  // {off0 | off1<<16, off2}
    uint2 fb = ftab[g];
    float3 A0 = ldsVertB(sv, fa.x & 0xFFFFu);
    float3 A1 = ldsVertB(sv, fa.x >> 16);
    float3 A2 = ldsVertB(sv, fa.y);
    float3 B0 = ldsVertB(sv, fb.x & 0xFFFFu);
    float3 B1 = ldsVertB(sv, fb.x >> 16);
    float3 B2 = ldsVertB(sv, fb.y);
    float pen = triPairPen(A0, A1, A2, B0, B1, B2);
    return r < 0 ? 0.0f : pen;
}

// ---------------- phase 0: pack face records (pre-shifted byte offsets) ----
__global__ __launch_bounds__(256) void pack_kernel(
    const int* __restrict__ faces,        // [NF, 3]
    uint2*     __restrict__ ftab)         // [NF]
{
    const int f = blockIdx.x * 256 + threadIdx.x;
    if (f >= NFF) return;
    const unsigned int o0 = (unsigned int)(faces[3 * f + 0] << 3);
    const unsigned int o1 = (unsigned int)(faces[3 * f + 1] << 3);
    const unsigned int o2 = (unsigned int)(faces[3 * f + 2] << 3);
    ftab[f] = make_uint2(o0 | (o1 << 16), o2);
}

// ---------------- fused: verts-only LDS (2 blocks/CU), eval pairs ----------
__global__ __launch_bounds__(THREADS, 8) void fused_kernel(
    const float* __restrict__ vertices,   // [B, NV, 3]
    const uint2* __restrict__ ftab,       // [NF] packed byte-offset records
    const int*   __restrict__ cidx,       // [B, NC, 2]
    float*       __restrict__ partials)   // [NBLOCK]
{
    // 55,120 + 64 = 55,184 B  -> floor(160K / 55.2K) = 2 blocks/CU
    __shared__ h4    s_v[NVV];            // fp16 vertex (x,y,z,pad), byte off = v*8
    __shared__ float s_red[16];

    const int b   = blockIdx.x;           // x-major dispatch -> XCD b%8
    const int sl  = blockIdx.y;
    const int tid = threadIdx.x;

    // ---- stage vertices: f32 global -> fp16 half4 LDS ----
    const float* vb = vertices + (size_t)b * (NVV * 3);
    for (int v = tid; v < NVV; v += THREADS) {
        const float* p = vb + 3 * v;
        h4 h;
        h.x = (_Float16)p[0];
        h.y = (_Float16)p[1];
        h.z = (_Float16)p[2];
        h.w = (_Float16)0.0f;
        s_v[v] = h;
    }
    __syncthreads();

    // ---- pair loop: 2 pairs per int4 load ----
    float pen = 0.0f;
    const v4i* c4 = (const v4i*)(cidx + ((size_t)b * NCC + (size_t)sl * PAIRS_PER_SLOT) * 2);
    for (int q = tid; q < QUADS; q += THREADS) {
        v4i pr = __builtin_nontemporal_load(c4 + q);   // {recv0, intr0, recv1, intr1}
        float p0 = pairPen(s_v, ftab, pr.x, pr.y);
        float p1 = pairPen(s_v, ftab, pr.z, pr.w);
        pen += p0 + p1;
    }

    // ---- block reduction: 16 waves ----
#pragma unroll
    for (int off = 32; off > 0; off >>= 1)
        pen += __shfl_down(pen, off, 64);
    const int lane = tid & 63;
    const int wv   = tid >> 6;
    if (lane == 0) s_red[wv] = pen;
    __syncthreads();
    if (tid == 0) {
        float t = 0.0f;
#pragma unroll
        for (int w = 0; w < 16; ++w) t += s_red[w];
        partials[b * SLOTS + sl] = t;
    }
}

// ---------------- fold 512 partials, apply weight / B ----------------
__global__ __launch_bounds__(512) void fin2_kernel(
    const float* __restrict__ partials,
    const float* __restrict__ weight,
    float*       __restrict__ out)
{
    float s = partials[threadIdx.x];      // NBLOCK == 512
#pragma unroll
    for (int off = 32; off > 0; off >>= 1)
        s += __shfl_down(s, off, 64);
    __shared__ float smem[8];
    const int lane = threadIdx.x & 63;
    const int wv   = threadIdx.x >> 6;
    if (lane == 0) smem[wv] = s;
    __syncthreads();
    if (threadIdx.x == 0) {
        float t = 0.0f;
#pragma unroll
        for (int w = 0; w < 8; ++w) t += smem[w];
        out[0] = t * weight[0] * (1.0f / (float)BB);
    }
}

// ---------------- fallback: direct per-pair with atomics (tiny ws) --------
__global__ void init_kernel(float* __restrict__ accum) { accum[0] = 0.0f; }

__global__ __launch_bounds__(256) void pen_direct(
    const float* __restrict__ vertices, const int* __restrict__ faces,
    const int2* __restrict__ cidx, float* __restrict__ accum)
{
    const int i = blockIdx.x * blockDim.x + threadIdx.x;
    float pen = 0.0f;
    if (i < BB * NCC) {
        const int b = i / NCC;
        const int2 pr = cidx[i];
        if (pr.x >= 0) {
            const int f0 = pr.x;
            const int f1 = pr.y < 0 ? 0 : pr.y;
            const float* vb = vertices + (size_t)b * (NVV * 3);
            float3 a0 = loadv3(vb + (size_t)faces[f0*3+0] * 3);
            float3 a1 = loadv3(vb + (size_t)faces[f0*3+1] * 3);
            float3 a2 = loadv3(vb + (size_t)faces[f0*3+2] * 3);
            float3 b0 = loadv3(vb + (size_t)faces[f1*3+0] * 3);
            float3 b1 = loadv3(vb + (size_t)faces[f1*3+1] * 3);
            float3 b2 = loadv3(vb + (size_t)faces[f1*3+2] * 3);
            pen = triPairPen(a0, a1, a2, b0, b1, b2);
        }
    }
#pragma unroll
    for (int off = 32; off > 0; off >>= 1)
        pen += __shfl_down(pen, off, 64);
    __shared__ float smem[4];
    const int lane = threadIdx.x & 63;
    const int wv   = threadIdx.x >> 6;
    if (lane == 0) smem[wv] = pen;
    __syncthreads();
    if (threadIdx.x == 0)
        atomicAdd(accum, smem[0] + smem[1] + smem[2] + smem[3]);
}

__global__ void fin_kernel(const float* __restrict__ accum,
                           const float* __restrict__ weight,
                           float* __restrict__ out)
{
    out[0] = accum[0] * weight[0] * (1.0f / (float)BB);
}

extern "C" void kernel_launch(void* const* d_in, const int* in_sizes, int n_in,
                              void* d_out, int out_size, void* d_ws, size_t ws_size,
                              hipStream_t stream) {
    const float* vertices = (const float*)d_in[4];
    const float* weight   = (const float*)d_in[5];
    const int*   faces    = (const int*)d_in[6];
    const int*   cidx     = (const int*)d_in[7];
    float* out = (float*)d_out;

    if (ws_size >= WS_NEED) {
        uint2* ftab     = (uint2*)d_ws;
        float* partials = (float*)((char*)d_ws + FTAB_BYTES);

        pack_kernel<<<dim3((NFF + 255) / 256), dim3(256), 0, stream>>>(faces, ftab);
        fused_kernel<<<dim3(BB, SLOTS), dim3(THREADS), 0, stream>>>(
            vertices, ftab, cidx, partials);
        fin2_kernel<<<dim3(1), dim3(512), 0, stream>>>(partials, weight, out);
    } else {
        float* accum = (float*)d_ws;
        const int totalPairs = BB * NCC;
        init_kernel<<<dim3(1), dim3(1), 0, stream>>>(accum);
        pen_direct<<<dim3((totalPairs + 255) / 256), dim3(256), 0, stream>>>(
            vertices, faces, (const int2*)cidx, accum);
        fin_kernel<<<dim3(1), dim3(1), 0, stream>>>(accum, weight, out);
    }
}

// Round 6
// 119.733 us; speedup vs baseline: 1.1325x; 1.1325x over previous
//
#include <hip/hip_runtime.h>

#define SIGMA 0.5f
#define BB 32
#define NVV 6890
#define NFF 13776
#define MAXC 8
#define NCC (NFF * MAXC)                 // 110208 pairs per batch

// fused kernel geometry: one block per (batch, slot); 16 slots per batch.
// LDS = verts only (55.2 KB) -> 2 blocks/CU by LDS; keep VGPR <= 64 so the
// HW reaches 2 blocks/CU (8 waves/SIMD) WITHOUT a launch_bounds min-waves
// hint (the ",8" hint made the allocator budget 32 VGPR and spill 26 MB to
// scratch in round 5 -- never hint, let resource arithmetic do it).
#define SLOTS 16
#define PAIRS_PER_SLOT (NCC / SLOTS)     // 6888 exactly
#define QUADS (PAIRS_PER_SLOT / 2)       // 3444 int4-quads (2 pairs each)
#define THREADS 1024
#define NBLOCK (BB * SLOTS)              // 512 blocks

// workspace layout: packed face table (u64 recs), then partials
#define FTAB_BYTES ((size_t)NFF * 8)     // 110,208 B
#define WS_NEED (FTAB_BYTES + (size_t)NBLOCK * 4 + 64)

typedef int       v4i __attribute__((ext_vector_type(4)));
typedef _Float16  h4  __attribute__((ext_vector_type(4)));

__device__ __forceinline__ float3 loadv3(const float* __restrict__ p) {
    return make_float3(p[0], p[1], p[2]);
}

// raw-instruction transcendentals (v_sqrt_f32 / v_rcp_f32, ~1 ulp)
__device__ __forceinline__ float fsqrt(float x) { return __builtin_amdgcn_sqrtf(x); }
__device__ __forceinline__ float frcp(float x)  { return __builtin_amdgcn_rcpf(x); }

// one-sided conic penetration, BRANCHLESS (round-3 known-good f32 core)
__device__ __forceinline__ float coneSide(float cx, float cy, float cz,
                                          float nx, float ny, float nz,
                                          float3 q0, float3 q1, float3 q2) {
    float pen = 0.0f;
#pragma unroll
    for (int v = 0; v < 3; ++v) {
        float3 q = (v == 0) ? q0 : ((v == 1) ? q1 : q2);
        float dx = q.x - cx, dy = q.y - cy, dz = q.z - cz;
        float h  = dx * nx + dy * ny + dz * nz;
        float r2 = dx * dx + dy * dy + dz * dz;
        float r  = fsqrt(r2);
        float phi = fmaxf(SIGMA - r, 0.0f);
        float hm  = fminf(h, 0.0f);          // (h<0 ? phi*h*h : 0) == phi*hm*hm
        pen = fmaf(phi * hm, hm, pen);
    }
    return pen;
}

__device__ __forceinline__ float triPairPen(float3 A0, float3 A1, float3 A2,
                                            float3 B0, float3 B1, float3 B2) {
    const float third = 1.0f / 3.0f;
    float cax = (A0.x + A1.x + A2.x) * third;
    float cay = (A0.y + A1.y + A2.y) * third;
    float caz = (A0.z + A1.z + A2.z) * third;
    float cbx = (B0.x + B1.x + B2.x) * third;
    float cby = (B0.y + B1.y + B2.y) * third;
    float cbz = (B0.z + B1.z + B2.z) * third;
    float e1x = A1.x - A0.x, e1y = A1.y - A0.y, e1z = A1.z - A0.z;
    float e2x = A2.x - A0.x, e2y = A2.y - A0.y, e2z = A2.z - A0.z;
    float nax = e1y * e2z - e1z * e2y;
    float nay = e1z * e2x - e1x * e2z;
    float naz = e1x * e2y - e1y * e2x;
    float inva = frcp(fsqrt(nax * nax + nay * nay + naz * naz) + 1e-8f);
    nax *= inva; nay *= inva; naz *= inva;
    float f1x = B1.x - B0.x, f1y = B1.y - B0.y, f1z = B1.z - B0.z;
    float f2x = B2.x - B0.x, f2y = B2.y - B0.y, f2z = B2.z - B0.z;
    float nbx = f1y * f2z - f1z * f2y;
    float nby = f1z * f2x - f1x * f2z;
    float nbz = f1x * f2y - f1y * f2x;
    float invb = frcp(fsqrt(nbx * nbx + nby * nby + nbz * nbz) + 1e-8f);
    nbx *= invb; nby *= invb; nbz *= invb;

    return coneSide(cax, cay, caz, nax, nay, naz, B0, B1, B2)
         + coneSide(cbx, cby, cbz, nbx, nby, nbz, A0, A1, A2);
}

// load one packed-f16 vertex by PRE-SHIFTED byte offset (one ds_read_b64)
__device__ __forceinline__ float3 ldsVertB(const h4* __restrict__ sv, unsigned int boff) {
    h4 h = *(const h4*)((const char*)sv + boff);
    return make_float3((float)h.x, (float)h.y, (float)h.z);
}

// branchless pair eval: face offsets from GLOBAL packed table (L2-warm),
// vertices from LDS. Invalid (r<0) masked with one cndmask.
__device__ __forceinline__ float pairPen(const h4*   __restrict__ sv,
                                         const uint2* __restrict__ ftab,
                                         int r, int it) {
    const int rr = r  < 0 ? 0 : r;
    const int g  = it < 0 ? 0 : it;       // reference clamps with max(idx,0)
    uint2 fa = ftab[rr];                  // {off0 | off1<<16, off2}
    uint2 fb = ftab[g];
    float3 A0 = ldsVertB(sv, fa.x & 0xFFFFu);
    float3 A1 = ldsVertB(sv, fa.x >> 16);
    float3 A2 = ldsVertB(sv, fa.y);
    float3 B0 = ldsVertB(sv, fb.x & 0xFFFFu);
    float3 B1 = ldsVertB(sv, fb.x >> 16);
    float3 B2 = ldsVertB(sv, fb.y);
    float pen = triPairPen(A0, A1, A2, B0, B1, B2);
    return r < 0 ? 0.0f : pen;
}

// ---------------- phase 0: pack face records (pre-shifted byte offsets) ----
__global__ __launch_bounds__(256) void pack_kernel(
    const int* __restrict__ faces,        // [NF, 3]
    uint2*     __restrict__ ftab)         // [NF]
{
    const int f = blockIdx.x * 256 + threadIdx.x;
    if (f >= NFF) return;
    const unsigned int o0 = (unsigned int)(faces[3 * f + 0] << 3);
    const unsigned int o1 = (unsigned int)(faces[3 * f + 1] << 3);
    const unsigned int o2 = (unsigned int)(faces[3 * f + 2] << 3);
    ftab[f] = make_uint2(o0 | (o1 << 16), o2);
}

// ---------------- fused: verts-only LDS (2 blocks/CU), eval pairs ----------
__global__ __launch_bounds__(THREADS) void fused_kernel(
    const float* __restrict__ vertices,   // [B, NV, 3]
    const uint2* __restrict__ ftab,       // [NF] packed byte-offset records
    const int*   __restrict__ cidx,       // [B, NC, 2]
    float*       __restrict__ partials)   // [NBLOCK]
{
    // 55,120 + 64 = 55,184 B  -> floor(160K / 55.2K) = 2 blocks/CU (by LDS)
    __shared__ h4    s_v[NVV];            // fp16 vertex (x,y,z,pad), byte off = v*8
    __shared__ float s_red[16];

    const int b   = blockIdx.x;           // x-major dispatch -> XCD b%8
    const int sl  = blockIdx.y;
    const int tid = threadIdx.x;

    // ---- stage vertices: f32 global -> fp16 half4 LDS ----
    const float* vb = vertices + (size_t)b * (NVV * 3);
    for (int v = tid; v < NVV; v += THREADS) {
        const float* p = vb + 3 * v;
        h4 h;
        h.x = (_Float16)p[0];
        h.y = (_Float16)p[1];
        h.z = (_Float16)p[2];
        h.w = (_Float16)0.0f;
        s_v[v] = h;
    }
    __syncthreads();

    // ---- pair loop: 2 pairs per int4 load ----
    float pen = 0.0f;
    const v4i* c4 = (const v4i*)(cidx + ((size_t)b * NCC + (size_t)sl * PAIRS_PER_SLOT) * 2);
    for (int q = tid; q < QUADS; q += THREADS) {
        v4i pr = __builtin_nontemporal_load(c4 + q);   // {recv0, intr0, recv1, intr1}
        float p0 = pairPen(s_v, ftab, pr.x, pr.y);
        float p1 = pairPen(s_v, ftab, pr.z, pr.w);
        pen += p0 + p1;
    }

    // ---- block reduction: 16 waves ----
#pragma unroll
    for (int off = 32; off > 0; off >>= 1)
        pen += __shfl_down(pen, off, 64);
    const int lane = tid & 63;
    const int wv   = tid >> 6;
    if (lane == 0) s_red[wv] = pen;
    __syncthreads();
    if (tid == 0) {
        float t = 0.0f;
#pragma unroll
        for (int w = 0; w < 16; ++w) t += s_red[w];
        partials[b * SLOTS + sl] = t;
    }
}

// ---------------- fold 512 partials, apply weight / B ----------------
__global__ __launch_bounds__(512) void fin2_kernel(
    const float* __restrict__ partials,
    const float* __restrict__ weight,
    float*       __restrict__ out)
{
    float s = partials[threadIdx.x];      // NBLOCK == 512
#pragma unroll
    for (int off = 32; off > 0; off >>= 1)
        s += __shfl_down(s, off, 64);
    __shared__ float smem[8];
    const int lane = threadIdx.x & 63;
    const int wv   = threadIdx.x >> 6;
    if (lane == 0) smem[wv] = s;
    __syncthreads();
    if (threadIdx.x == 0) {
        float t = 0.0f;
#pragma unroll
        for (int w = 0; w < 8; ++w) t += smem[w];
        out[0] = t * weight[0] * (1.0f / (float)BB);
    }
}

// ---------------- fallback: direct per-pair with atomics (tiny ws) --------
__global__ void init_kernel(float* __restrict__ accum) { accum[0] = 0.0f; }

__global__ __launch_bounds__(256) void pen_direct(
    const float* __restrict__ vertices, const int* __restrict__ faces,
    const int2* __restrict__ cidx, float* __restrict__ accum)
{
    const int i = blockIdx.x * blockDim.x + threadIdx.x;
    float pen = 0.0f;
    if (i < BB * NCC) {
        const int b = i / NCC;
        const int2 pr = cidx[i];
        if (pr.x >= 0) {
            const int f0 = pr.x;
            const int f1 = pr.y < 0 ? 0 : pr.y;
            const float* vb = vertices + (size_t)b * (NVV * 3);
            float3 a0 = loadv3(vb + (size_t)faces[f0*3+0] * 3);
            float3 a1 = loadv3(vb + (size_t)faces[f0*3+1] * 3);
            float3 a2 = loadv3(vb + (size_t)faces[f0*3+2] * 3);
            float3 b0 = loadv3(vb + (size_t)faces[f1*3+0] * 3);
            float3 b1 = loadv3(vb + (size_t)faces[f1*3+1] * 3);
            float3 b2 = loadv3(vb + (size_t)faces[f1*3+2] * 3);
            pen = triPairPen(a0, a1, a2, b0, b1, b2);
        }
    }
#pragma unroll
    for (int off = 32; off > 0; off >>= 1)
        pen += __shfl_down(pen, off, 64);
    __shared__ float smem[4];
    const int lane = threadIdx.x & 63;
    const int wv   = threadIdx.x >> 6;
    if (lane == 0) smem[wv] = pen;
    __syncthreads();
    if (threadIdx.x == 0)
        atomicAdd(accum, smem[0] + smem[1] + smem[2] + smem[3]);
}

__global__ void fin_kernel(const float* __restrict__ accum,
                           const float* __restrict__ weight,
                           float* __restrict__ out)
{
    out[0] = accum[0] * weight[0] * (1.0f / (float)BB);
}

extern "C" void kernel_launch(void* const* d_in, const int* in_sizes, int n_in,
                              void* d_out, int out_size, void* d_ws, size_t ws_size,
                              hipStream_t stream) {
    const float* vertices = (const float*)d_in[4];
    const float* weight   = (const float*)d_in[5];
    const int*   faces    = (const int*)d_in[6];
    const int*   cidx     = (const int*)d_in[7];
    float* out = (float*)d_out;

    if (ws_size >= WS_NEED) {
        uint2* ftab     = (uint2*)d_ws;
        float* partials = (float*)((char*)d_ws + FTAB_BYTES);

        pack_kernel<<<dim3((NFF + 255) / 256), dim3(256), 0, stream>>>(faces, ftab);
        fused_kernel<<<dim3(BB, SLOTS), dim3(THREADS), 0, stream>>>(
            vertices, ftab, cidx, partials);
        fin2_kernel<<<dim3(1), dim3(512), 0, stream>>>(partials, weight, out);
    } else {
        float* accum = (float*)d_ws;
        const int totalPairs = BB * NCC;
        init_kernel<<<dim3(1), dim3(1), 0, stream>>>(accum);
        pen_direct<<<dim3((totalPairs + 255) / 256), dim3(256), 0, stream>>>(
            vertices, faces, (const int2*)cidx, accum);
        fin_kernel<<<dim3(1), dim3(1), 0, stream>>>(accum, weight, out);
    }
}